// Round 12
// baseline (20445.656 us; speedup 1.0000x reference)
//
#include <hip/hip_runtime.h>

// ============================================================================
// Seq2Seq (bi-LSTM encoder + Bahdanau-attention LSTM decoder) on gfx950.
// fp32 in/out; fp16 internal (fp32 accum/state).
// R12 = R11 (13.06 ms) with the 254-launch decoder chain replaced by ONE
// persistent kernel (256 blocks = 1/CU) using a FIXED grid barrier:
//   R5's barrier polled with agent-ACQUIRE (buffer_inv per poll -> L1-inv
//   storm, 163 us/step).  R12 polls RELAXED and issues a single acquire
//   fence after the flip; producer side keeps RELEASE on the counter add.
// Att/gates phase bodies are verbatim R11 (proven shapes, proven absmax).
// ============================================================================

typedef _Float16 f16;
typedef _Float16 half8 __attribute__((ext_vector_type(8)));
typedef float f32x4 __attribute__((ext_vector_type(4)));
typedef char char8v __attribute__((ext_vector_type(8)));

#define MFMA16(a, b, c) __builtin_amdgcn_mfma_f32_16x16x32_f16((a), (b), (c), 0, 0, 0)

#define PSCALE (2.5f / 127.f)
#define PINV   (127.f / 2.5f)

__device__ __forceinline__ float fsig(float x) {
    return __builtin_amdgcn_rcpf(1.f + __expf(-x));
}
__device__ __forceinline__ float ftanh(float x) {
    return 1.f - 2.f * __builtin_amdgcn_rcpf(1.f + __expf(2.f * x));
}
__device__ __forceinline__ int frag_idx(int m, int k, int KS) {
    return (((m >> 4) * KS + (k >> 5)) * 64 + (((k >> 3) & 3) * 16 + (m & 15))) * 8 + (k & 7);
}

// Grid barrier: RELAXED polling (no per-poll cache invalidate), one acquire
// fence after the generation flips.  Producer publish: RELEASE fetch_add.
__device__ __forceinline__ void gridbar(int* cnt, int* gen, int nblk) {
    __syncthreads();
    if (threadIdx.x == 0) {
        int g = __hip_atomic_load(gen, __ATOMIC_RELAXED, __HIP_MEMORY_SCOPE_AGENT);
        int v = __hip_atomic_fetch_add(cnt, 1, __ATOMIC_RELEASE, __HIP_MEMORY_SCOPE_AGENT);
        if (v == nblk - 1) {
            __hip_atomic_store(cnt, 0, __ATOMIC_RELAXED, __HIP_MEMORY_SCOPE_AGENT);
            __hip_atomic_fetch_add(gen, 1, __ATOMIC_RELEASE, __HIP_MEMORY_SCOPE_AGENT);
        } else {
            while (__hip_atomic_load(gen, __ATOMIC_RELAXED, __HIP_MEMORY_SCOPE_AGENT) == g)
                __builtin_amdgcn_s_sleep(2);
        }
        __builtin_amdgcn_fence(__ATOMIC_ACQUIRE, "agent");
    }
    __syncthreads();
}

// ---------------------------------------------------------------------------
// K0: one-shot transforms + zero sync counters.
// ---------------------------------------------------------------------------
__global__ __launch_bounds__(256) void k_prep(
    const float* __restrict__ attn_W, const float* __restrict__ out_W,
    const float* __restrict__ enc_emb,
    const float* __restrict__ wihf, const float* __restrict__ wihb,
    const float* __restrict__ whhf, const float* __restrict__ whhb,
    const float* __restrict__ dec_emb, const float* __restrict__ dec_wih,
    const float* __restrict__ dec_whh,
    f16* __restrict__ WhT_sw, f16* __restrict__ outWT_sw,
    f16* __restrict__ whhf_sw, f16* __restrict__ whhb_sw,
    f16* __restrict__ decwih_sw, f16* __restrict__ decwhh_sw,
    f16* __restrict__ WeT, f16* __restrict__ emb16,
    f16* __restrict__ wihf16, f16* __restrict__ wihb16,
    f16* __restrict__ decemb16, float* __restrict__ out,
    int* __restrict__ syncb)
{
    long i = (long)blockIdx.x * 256 + threadIdx.x;
    if (i >= 3784768L) return;
    long idx = i;
    if (idx < 262144) {
        int j = idx & 7, lane = (idx >> 3) & 63, c = lane & 15, q = lane >> 4;
        int ks = (idx >> 9) & 15, nt = idx >> 13;
        WhT_sw[idx] = (f16)attn_W[(ks * 32 + q * 8 + j) * 512 + nt * 16 + c];
        return;
    }
    idx -= 262144;
    if (idx < 65536) {
        int j = idx & 7, lane = (idx >> 3) & 63, c = lane & 15, q = lane >> 4;
        int ks = (idx >> 9) & 15, nt = idx >> 13;
        outWT_sw[idx] = (f16)out_W[(ks * 32 + q * 8 + j) * 128 + nt * 16 + c];
        return;
    }
    idx -= 65536;
    if (idx < 262144) {
        int j = idx & 7, lane = (idx >> 3) & 63, c = lane & 15, q = lane >> 4;
        int ks = (idx >> 9) & 7, nt = idx >> 12;
        whhf_sw[idx] = (f16)whhf[(nt * 16 + c) * 256 + ks * 32 + q * 8 + j];
        return;
    }
    idx -= 262144;
    if (idx < 262144) {
        int j = idx & 7, lane = (idx >> 3) & 63, c = lane & 15, q = lane >> 4;
        int ks = (idx >> 9) & 7, nt = idx >> 12;
        whhb_sw[idx] = (f16)whhb[(nt * 16 + c) * 256 + ks * 32 + q * 8 + j];
        return;
    }
    idx -= 262144;
    if (idx < 1310720) {
        int j = idx & 7, lane = (idx >> 3) & 63, c = lane & 15, q = lane >> 4;
        int r2 = idx >> 9; int ks = r2 % 20, nt = r2 / 20;
        decwih_sw[idx] = (f16)dec_wih[(nt * 16 + c) * 640 + ks * 32 + q * 8 + j];
        return;
    }
    idx -= 1310720;
    if (idx < 1048576) {
        int j = idx & 7, lane = (idx >> 3) & 63, c = lane & 15, q = lane >> 4;
        int ks = (idx >> 9) & 15, nt = idx >> 13;
        decwhh_sw[idx] = (f16)dec_whh[(nt * 16 + c) * 512 + ks * 32 + q * 8 + j];
        return;
    }
    idx -= 1048576;
    if (idx < 262144) { int e = idx >> 9, d = idx & 511; WeT[idx] = (f16)attn_W[(512 + d) * 512 + e]; return; }
    idx -= 262144;
    if (idx < 16384)  { emb16[idx] = (f16)enc_emb[idx]; return; }
    idx -= 16384;
    if (idx < 131072) { wihf16[idx] = (f16)wihf[idx]; return; }
    idx -= 131072;
    if (idx < 131072) { wihb16[idx] = (f16)wihb[idx]; return; }
    idx -= 131072;
    if (idx < 16384)  { decemb16[idx] = (f16)dec_emb[idx]; return; }
    idx -= 16384;
    if (idx < 16384)  { int b = idx >> 7, v = idx & 127; out[b * 16384 + v] = 0.f; return; }
    idx -= 16384;
    if (idx < 64)     { syncb[idx] = 0; return; }
}

// ---------------------------------------------------------------------------
// K_vocab (once).
// ---------------------------------------------------------------------------
__global__ __launch_bounds__(256) void k_vocab(
    const f16* __restrict__ emb, const f16* __restrict__ wihf,
    const f16* __restrict__ wihb, const float* __restrict__ bf_,
    const float* __restrict__ bb_, f16* __restrict__ xg_vocab)
{
    int bn = blockIdx.x;
    int tid = threadIdx.x, wave = tid >> 6, lane = tid & 63;
    int col = lane & 15, quad = lane >> 4;
    int wr = wave >> 1, wc = wave & 1;

    f32x4 acc[4][4] = {};
    for (int ks = 0; ks < 4; ++ks) {
        int k0 = ks * 32 + quad * 8;
        half8 a[4], bfr[4];
        for (int i = 0; i < 4; ++i)
            a[i] = *(const half8*)(emb + (wr * 64 + i * 16 + col) * 128 + k0);
        for (int j = 0; j < 4; ++j) {
            int n = bn * 128 + wc * 64 + j * 16 + col;
            const f16* wp = (n < 1024) ? (wihf + n * 128) : (wihb + (n - 1024) * 128);
            bfr[j] = *(const half8*)(wp + k0);
        }
        for (int i = 0; i < 4; ++i)
            for (int j = 0; j < 4; ++j)
                acc[i][j] = MFMA16(a[i], bfr[j], acc[i][j]);
    }
    for (int j = 0; j < 4; ++j) {
        int n = bn * 128 + wc * 64 + j * 16 + col;
        float bias = (n < 1024) ? bf_[n] : bb_[n - 1024];
        for (int i = 0; i < 4; ++i) {
            int vbase = wr * 64 + i * 16 + quad * 4;
            for (int r = 0; r < 4; ++r)
                xg_vocab[(vbase + r) * 2048 + n] = (f16)(acc[i][j][r] + bias);
        }
    }
}

// ---------------------------------------------------------------------------
// K_enc (R10 -- known correct).
// ---------------------------------------------------------------------------
__global__ __launch_bounds__(512, 2) void k_enc(
    const int* __restrict__ src, const f16* __restrict__ xg_vocab,
    const f16* __restrict__ whhf_sw, const f16* __restrict__ whhb_sw,
    f16* __restrict__ enc_out, f16* __restrict__ hdec0, float* __restrict__ c_ws)
{
    int blk = blockIdx.x;
    int dir = blk >> 3, bbase = (blk & 7) * 16;
    int tid = threadIdx.x, wave = tid >> 6, lane = tid & 63;
    int col = lane & 15, quad = lane >> 4;
    const f16* whh = dir ? whhb_sw : whhf_sw;

    __shared__ f16 hb[16][264];
    __shared__ f16 xvb[16][1032];
    __shared__ int stok[16];
    for (int z = tid; z < 16 * 264; z += 512) ((f16*)hb)[z] = (f16)0.f;
    float cc[2][4] = {};

    half8 bst[32];
    #pragma unroll
    for (int g = 0; g < 2; ++g)
        #pragma unroll
        for (int nt = 0; nt < 2; ++nt)
            #pragma unroll
            for (int kk = 0; kk < 8; ++kk) {
                int tile = g * 16 + wave * 2 + nt;
                bst[(g * 2 + nt) * 8 + kk] =
                    *(const half8*)(whh + ((tile * 8 + kk) * 64 + lane) * 8);
            }
    __syncthreads();

    for (int t = 0; t < 512; ++t) {
        int ts = dir ? (511 - t) : t;
        if (tid < 16) stok[tid] = src[(bbase + tid) * 512 + ts];
        half8 a[8];
        #pragma unroll
        for (int kk = 0; kk < 8; ++kk)
            a[kk] = *(const half8*)(&hb[col][kk * 32 + quad * 8]);
        __syncthreads();

        #pragma unroll
        for (int it = 0; it < 4; ++it) {
            int cnk = it * 512 + tid;
            int row = cnk >> 7, off = (cnk & 127) * 8;
            *(half8*)(&xvb[row][off]) =
                *(const half8*)(xg_vocab + stok[row] * 2048 + dir * 1024 + off);
        }

        f32x4 acc[4][2] = {};
        #pragma unroll
        for (int kk = 0; kk < 8; ++kk) {
            half8 bv[4];
            #pragma unroll
            for (int g = 2; g < 4; ++g)
                #pragma unroll
                for (int nt = 0; nt < 2; ++nt) {
                    int tile = g * 16 + wave * 2 + nt;
                    bv[(g - 2) * 2 + nt] =
                        *(const half8*)(whh + ((tile * 8 + kk) * 64 + lane) * 8);
                }
            #pragma unroll
            for (int g = 0; g < 2; ++g)
                #pragma unroll
                for (int nt = 0; nt < 2; ++nt)
                    acc[g][nt] = MFMA16(a[kk], bst[(g * 2 + nt) * 8 + kk], acc[g][nt]);
            #pragma unroll
            for (int g = 2; g < 4; ++g)
                #pragma unroll
                for (int nt = 0; nt < 2; ++nt)
                    acc[g][nt] = MFMA16(a[kk], bv[(g - 2) * 2 + nt], acc[g][nt]);
        }
        __syncthreads();

        #pragma unroll
        for (int nt = 0; nt < 2; ++nt) {
            int hcol = wave * 32 + nt * 16 + col;
            #pragma unroll
            for (int r = 0; r < 4; ++r) {
                int b = quad * 4 + r;
                float gi = (float)xvb[b][0 * 256 + hcol] + acc[0][nt][r];
                float gf = (float)xvb[b][1 * 256 + hcol] + acc[1][nt][r];
                float gg = (float)xvb[b][2 * 256 + hcol] + acc[2][nt][r];
                float go = (float)xvb[b][3 * 256 + hcol] + acc[3][nt][r];
                float ig = fsig(gi), fg = fsig(gf), g2 = ftanh(gg), og = fsig(go);
                float cv = fg * cc[nt][r] + ig * g2;
                cc[nt][r] = cv;
                float h = og * ftanh(cv);
                f16 h16 = (f16)h;
                hb[b][hcol] = h16;
                enc_out[((size_t)(bbase + b) * 512 + ts) * 512 + dir * 256 + hcol] = h16;
            }
        }
        __syncthreads();
    }
    #pragma unroll
    for (int nt = 0; nt < 2; ++nt) {
        int hcol = wave * 32 + nt * 16 + col;
        #pragma unroll
        for (int r = 0; r < 4; ++r) {
            int b = quad * 4 + r;
            int m = bbase + b, k = dir * 256 + hcol;
            hdec0[frag_idx(m, k, 16)] = hb[b][hcol];
            c_ws[m * 512 + k] = cc[nt][r];
        }
    }
}

// ---------------------------------------------------------------------------
// K_proj (once): writes int8 proj.
// ---------------------------------------------------------------------------
__global__ __launch_bounds__(256) void k_proj(
    const f16* __restrict__ enc_out, const f16* __restrict__ WeT,
    char* __restrict__ proj8)
{
    int blk = blockIdx.x;
    int bm = blk & 511, bn = blk >> 9;
    int tid = threadIdx.x, wave = tid >> 6, lane = tid & 63;
    int col = lane & 15, quad = lane >> 4;
    int wr = wave >> 1, wc = wave & 1;

    f32x4 acc[4][4] = {};
    for (int ks = 0; ks < 16; ++ks) {
        int k0 = ks * 32 + quad * 8;
        half8 a[4], bfr[4];
        for (int i = 0; i < 4; ++i) {
            int m = bm * 128 + wr * 64 + i * 16 + col;
            a[i] = *(const half8*)(enc_out + (size_t)m * 512 + k0);
        }
        for (int j = 0; j < 4; ++j) {
            int n = bn * 128 + wc * 64 + j * 16 + col;
            bfr[j] = *(const half8*)(WeT + n * 512 + k0);
        }
        for (int i = 0; i < 4; ++i)
            for (int j = 0; j < 4; ++j)
                acc[i][j] = MFMA16(a[i], bfr[j], acc[i][j]);
    }
    for (int j = 0; j < 4; ++j) {
        int n = bn * 128 + wc * 64 + j * 16 + col;
        for (int i = 0; i < 4; ++i) {
            int mbase = bm * 128 + wr * 64 + i * 16 + quad * 4;
            for (int r = 0; r < 4; ++r) {
                float v = acc[i][j][r] * PINV;
                int q = (int)rintf(v);
                q = (q > 127) ? 127 : ((q < -127) ? -127 : q);
                proj8[(size_t)(mbase + r) * 512 + n] = (char)q;
            }
        }
    }
}

// ---------------------------------------------------------------------------
// K_qinit (once).
// ---------------------------------------------------------------------------
__global__ __launch_bounds__(256) void k_qinit(
    const f16* __restrict__ h0_sw, const f16* __restrict__ WhT_sw,
    float* __restrict__ qpart)
{
    int j = blockIdx.x;
    int tid = threadIdx.x, wave = tid >> 6, lane = tid & 63;
    int col = lane & 15, quad = lane >> 4;
    half8 a[2];
    #pragma unroll
    for (int i = 0; i < 2; ++i)
        a[i] = *(const half8*)(h0_sw + (((wave * 2 + i) * 16 + j) * 64 + lane) * 8);
    for (int nt = 0; nt < 32; ++nt) {
        half8 bfr = *(const half8*)(WhT_sw + ((nt * 16 + j) * 64 + lane) * 8);
        f32x4 q0 = {}, q1 = {};
        q0 = MFMA16(a[0], bfr, q0);
        q1 = MFMA16(a[1], bfr, q1);
        #pragma unroll
        for (int r = 0; r < 4; ++r) {
            qpart[(j * 128 + wave * 32 + quad * 4 + r) * 512 + nt * 16 + col] = q0[r];
            qpart[(j * 128 + wave * 32 + 16 + quad * 4 + r) * 512 + nt * 16 + col] = q1[r];
        }
    }
}

// ---------------------------------------------------------------------------
// K_dec: persistent decoder.  256 blocks x 512 thr (1 block/CU).  Per step:
// ATT phase (verbatim R11 k_att; block = (b, sh)) | gridbar |
// GATES phase (verbatim R11 k_gates on blocks 0-31; widened to 512 thr with
// barriers outside guards) | gridbar.
// ---------------------------------------------------------------------------
__global__ __launch_bounds__(512, 2) void k_dec(
    const char* __restrict__ proj8, const f16* __restrict__ enc_out,
    float* __restrict__ qpart, const float* __restrict__ attn_b,
    const float* __restrict__ attn_v, const int* __restrict__ trg,
    const f16* __restrict__ decemb, f16* __restrict__ x_sw,
    const f16* __restrict__ wih_sw, const f16* __restrict__ whh_sw,
    const float* __restrict__ dec_b, float* __restrict__ c_ws,
    f16* __restrict__ hd0, f16* __restrict__ hd1, f16* __restrict__ hhist_sw,
    const f16* __restrict__ WhT_sw,
    float* __restrict__ part_m, float* __restrict__ part_l,
    float* __restrict__ part_ctx, int* __restrict__ syncb)
{
    int blk = blockIdx.x;
    int b = blk >> 1, sh = blk & 1;
    int tid = threadIdx.x, wave = tid >> 6, lane = tid & 63;
    int col = lane & 15, quad = lane >> 4;
    int nblk = gridDim.x;
    int* cnt = syncb;
    int* gen = syncb + 16;

    __shared__ float q[512];
    __shared__ float sc[256];
    __shared__ float ctxred[8][512];
    __shared__ float wred[8], wred2[8];
    __shared__ f16 hsl[64][40];
    __shared__ float gm[64][2];

    // gates-phase constants (blocks 0-31)
    int gj = blk >> 1, gmh = blk & 1;
    float bias[8];
    if (blk < 32) {
        #pragma unroll
        for (int jt = 0; jt < 8; ++jt) {
            int g = jt >> 1, u2 = jt & 1;
            bias[jt] = dec_b[g * 512 + gj * 32 + u2 * 16 + col];
        }
    }
    float vreg[8];
    #pragma unroll
    for (int u = 0; u < 8; ++u) vreg[u] = attn_v[lane * 8 + u];
    int sbase = sh * 256;

    for (int t = 0; t < 127; ++t) {
        // ======================= ATT phase (all 256 blocks) =======================
        {
            float s = attn_b[tid];
            #pragma unroll
            for (int jj = 0; jj < 16; ++jj) s += qpart[(jj * 128 + b) * 512 + tid];
            q[tid] = s;
        }
        __syncthreads();

        float qreg[8];
        #pragma unroll
        for (int u = 0; u < 8; ++u) qreg[u] = q[lane * 8 + u];

        for (int ib = 0; ib < 4; ++ib) {
            char8v p[8];
            #pragma unroll
            for (int z = 0; z < 8; ++z) {
                int sl = (ib * 8 + z) * 8 + wave;
                p[z] = *(const char8v*)(proj8 + ((size_t)b * 512 + sbase + sl) * 512 + lane * 8);
            }
            #pragma unroll
            for (int z = 0; z < 8; ++z) {
                int sl = (ib * 8 + z) * 8 + wave;
                float part = 0.f;
                #pragma unroll
                for (int u = 0; u < 8; ++u)
                    part += vreg[u] * ftanh(fmaf((float)p[z][u], PSCALE, qreg[u]));
                #pragma unroll
                for (int o = 32; o; o >>= 1) part += __shfl_xor(part, o);
                if (lane == 0) sc[sl] = part;
            }
        }
        __syncthreads();

        float s0 = (tid < 256) ? sc[tid] : -__builtin_inff();
        float mv = s0;
        #pragma unroll
        for (int o = 32; o; o >>= 1) mv = fmaxf(mv, __shfl_xor(mv, o));
        if (lane == 0) wred[wave] = mv;
        __syncthreads();
        float M = wred[0];
        #pragma unroll
        for (int w = 1; w < 8; ++w) M = fmaxf(M, wred[w]);
        float e0 = (tid < 256) ? __expf(s0 - M) : 0.f;
        if (tid < 256) sc[tid] = e0;
        float sm = e0;
        #pragma unroll
        for (int o = 32; o; o >>= 1) sm += __shfl_xor(sm, o);
        if (lane == 0) wred2[wave] = sm;
        __syncthreads();
        float lb2 = wred2[0];
        #pragma unroll
        for (int w = 1; w < 8; ++w) lb2 += wred2[w];

        float a8[8] = {};
        for (int ib = 0; ib < 4; ++ib) {
            half8 ev[8];
            float wgt[8];
            #pragma unroll
            for (int z = 0; z < 8; ++z) {
                int sl = (ib * 8 + z) * 8 + wave;
                ev[z] = *(const half8*)(enc_out + ((size_t)b * 512 + sbase + sl) * 512 + lane * 8);
                wgt[z] = sc[sl];
            }
            #pragma unroll
            for (int z = 0; z < 8; ++z)
                #pragma unroll
                for (int u = 0; u < 8; ++u) a8[u] += wgt[z] * (float)ev[z][u];
        }
        #pragma unroll
        for (int u = 0; u < 8; ++u) ctxred[wave][lane * 8 + u] = a8[u];
        __syncthreads();
        float cp = 0.f;
        #pragma unroll
        for (int w = 0; w < 8; ++w) cp += ctxred[w][tid];
        part_ctx[(size_t)blk * 512 + tid] = cp;
        if (tid == 0) { part_m[blk] = M; part_l[blk] = lb2; }

        if (sh == 0 && tid < 128) {
            int tok = trg[b * 128 + t];
            x_sw[frag_idx(b, tid, 20)] = decemb[tok * 128 + tid];
        }

        gridbar(cnt, gen, nblk);

        // ======================= GATES phase (blocks 0-31) =======================
        if (blk < 32 && tid < 64) {
            int bb = gmh * 64 + tid;
            float m0 = part_m[bb * 2 + 0], m1 = part_m[bb * 2 + 1];
            float l0 = part_l[bb * 2 + 0], l1 = part_l[bb * 2 + 1];
            float Mx = fmaxf(m0, m1);
            float g0 = __expf(m0 - Mx), g1 = __expf(m1 - Mx);
            float inv = 1.f / (g0 * l0 + g1 * l1);
            gm[tid][0] = g0 * inv;
            gm[tid][1] = g1 * inv;
        }
        __syncthreads();
        if (blk < 32) {
            for (int z = tid; z < 32768; z += 512) {
                int lr = z >> 9, d = z & 511;
                int bb = gmh * 64 + lr;
                float c = gm[lr][0] * part_ctx[(size_t)(bb * 2 + 0) * 512 + d]
                        + gm[lr][1] * part_ctx[(size_t)(bb * 2 + 1) * 512 + d];
                x_sw[frag_idx(bb, 128 + d, 20)] = (f16)c;
            }
        }
        __syncthreads();

        if (blk < 32 && wave < 4) {
            const f16* hprev = (t & 1) ? hd1 : hd0;
            f16* hnext = (t & 1) ? hd0 : hd1;

            f32x4 acc[8] = {};
            for (int ks = 0; ks < 36; ++ks) {
                int mtile = gmh * 4 + wave;
                half8 a = (ks < 20)
                    ? *(const half8*)(x_sw + ((mtile * 20 + ks) * 64 + lane) * 8)
                    : *(const half8*)(hprev + ((mtile * 16 + (ks - 20)) * 64 + lane) * 8);
                half8 bv[8];
                #pragma unroll
                for (int jt = 0; jt < 8; ++jt) {
                    int g = jt >> 1, u2 = jt & 1;
                    int ntile = g * 32 + gj * 2 + u2;
                    bv[jt] = (ks < 20)
                        ? *(const half8*)(wih_sw + ((ntile * 20 + ks) * 64 + lane) * 8)
                        : *(const half8*)(whh_sw + ((ntile * 16 + (ks - 20)) * 64 + lane) * 8);
                }
                #pragma unroll
                for (int jt = 0; jt < 8; ++jt)
                    acc[jt] = MFMA16(a, bv[jt], acc[jt]);
            }
            #pragma unroll
            for (int r = 0; r < 4; ++r) {
                int lr = wave * 16 + quad * 4 + r;
                int bb = gmh * 64 + lr;
                #pragma unroll
                for (int u2 = 0; u2 < 2; ++u2) {
                    int hl = u2 * 16 + col, hcol = gj * 32 + hl;
                    float gi = acc[0 + u2][r] + bias[0 + u2];
                    float gf = acc[2 + u2][r] + bias[2 + u2];
                    float gg = acc[4 + u2][r] + bias[4 + u2];
                    float go = acc[6 + u2][r] + bias[6 + u2];
                    float ig = fsig(gi), fg = fsig(gf), g2 = ftanh(gg), og = fsig(go);
                    float cv = fg * c_ws[bb * 512 + hcol] + ig * g2;
                    c_ws[bb * 512 + hcol] = cv;
                    float h = og * ftanh(cv);
                    f16 h16 = (f16)h;
                    int fidx = frag_idx(bb, hcol, 16);
                    hnext[fidx] = h16;
                    hhist_sw[t * 65536 + fidx] = h16;
                    hsl[lr][hl] = h16;
                }
            }
            half8 aq = *(const half8*)(&hsl[wave * 16 + col][quad * 8]);
            for (int nt = 0; nt < 32; ++nt) {
                half8 bq = *(const half8*)(WhT_sw + ((nt * 16 + gj) * 64 + lane) * 8);
                f32x4 q0 = {};
                q0 = MFMA16(aq, bq, q0);
                #pragma unroll
                for (int r = 0; r < 4; ++r)
                    qpart[(gj * 128 + gmh * 64 + wave * 16 + quad * 4 + r) * 512 + nt * 16 + col] = q0[r];
            }
        }

        gridbar(cnt, gen, nblk);
    }
}

// ---------------------------------------------------------------------------
// K_logits (once).
// ---------------------------------------------------------------------------
__global__ __launch_bounds__(256) void k_logits(
    const f16* __restrict__ hhist_sw, const f16* __restrict__ outWT_sw,
    const float* __restrict__ out_b, float* __restrict__ out)
{
    int bt = blockIdx.x;
    int tid = threadIdx.x, wave = tid >> 6, lane = tid & 63;
    int col = lane & 15, quad = lane >> 4;
    f32x4 acc[2][8] = {};
    for (int ks = 0; ks < 16; ++ks) {
        half8 a[2];
        #pragma unroll
        for (int i = 0; i < 2; ++i)
            a[i] = *(const half8*)(hhist_sw + bt * 65536 + (((wave * 2 + i) * 16 + ks) * 64 + lane) * 8);
        half8 bv[8];
        #pragma unroll
        for (int jt = 0; jt < 8; ++jt)
            bv[jt] = *(const half8*)(outWT_sw + ((jt * 16 + ks) * 64 + lane) * 8);
        #pragma unroll
        for (int jt = 0; jt < 8; ++jt) {
            acc[0][jt] = MFMA16(a[0], bv[jt], acc[0][jt]);
            acc[1][jt] = MFMA16(a[1], bv[jt], acc[1][jt]);
        }
    }
    #pragma unroll
    for (int jt = 0; jt < 8; ++jt) {
        float bias = out_b[jt * 16 + col];
        #pragma unroll
        for (int i = 0; i < 2; ++i)
            #pragma unroll
            for (int r = 0; r < 4; ++r) {
                int br = wave * 32 + i * 16 + quad * 4 + r;
                out[br * 16384 + (bt + 1) * 128 + jt * 16 + col] = acc[i][jt][r] + bias;
            }
    }
}

// ---------------------------------------------------------------------------
extern "C" void kernel_launch(void* const* d_in, const int* in_sizes, int n_in,
                              void* d_out, int out_size, void* d_ws, size_t ws_size,
                              hipStream_t stream)
{
    (void)in_sizes; (void)n_in; (void)out_size;
    if (ws_size < 130000000) return;

    const int*   src     = (const int*)d_in[0];
    const int*   trg     = (const int*)d_in[1];
    const float* enc_emb = (const float*)d_in[2];
    const float* wihf    = (const float*)d_in[3];
    const float* whhf    = (const float*)d_in[4];
    const float* bf_     = (const float*)d_in[5];
    const float* wihb    = (const float*)d_in[6];
    const float* whhb    = (const float*)d_in[7];
    const float* bb_     = (const float*)d_in[8];
    const float* dec_emb = (const float*)d_in[9];
    const float* dec_wih = (const float*)d_in[10];
    const float* dec_whh = (const float*)d_in[11];
    const float* dec_b   = (const float*)d_in[12];
    const float* attn_W  = (const float*)d_in[13];
    const float* attn_b  = (const float*)d_in[14];
    const float* attn_v  = (const float*)d_in[15];
    const float* out_W   = (const float*)d_in[16];
    const float* out_b   = (const float*)d_in[17];
    float* out = (float*)d_out;

    char* p = (char*)d_ws;
    auto carve = [&](size_t n) { char* r = p; p += ((n + 255) & ~(size_t)255); return r; };
    f16*   enc_out   = (f16*)  carve(67108864);
    char*  proj8     = (char*) carve(33554432);
    f16*   WhT_sw    = (f16*)  carve(524288);
    f16*   WeT       = (f16*)  carve(524288);
    f16*   outWT_sw  = (f16*)  carve(131072);
    f16*   emb16     = (f16*)  carve(32768);
    f16*   wihf16    = (f16*)  carve(262144);
    f16*   wihb16    = (f16*)  carve(262144);
    f16*   whhf_sw   = (f16*)  carve(524288);
    f16*   whhb_sw   = (f16*)  carve(524288);
    f16*   decemb16  = (f16*)  carve(32768);
    f16*   decwih_sw = (f16*)  carve(2621440);
    f16*   decwhh_sw = (f16*)  carve(2097152);
    float* qpart     = (float*)carve(4194304);
    f16*   hdec0     = (f16*)  carve(131072);
    f16*   hdec1     = (f16*)  carve(131072);
    float* c_ws      = (float*)carve(262144);
    f16*   x_sw      = (f16*)  carve(163840);
    f16*   hhist_sw  = (f16*)  carve(16646144);
    f16*   xg_vocab  = (f16*)  carve(524288);
    float* part_m    = (float*)carve(2048);
    float* part_l    = (float*)carve(2048);
    float* part_ctx  = (float*)carve(524288);
    int*   syncb     = (int*)  carve(256);

    k_prep<<<14785, 256, 0, stream>>>(attn_W, out_W, enc_emb, wihf, wihb, whhf, whhb,
                                      dec_emb, dec_wih, dec_whh,
                                      WhT_sw, outWT_sw, whhf_sw, whhb_sw,
                                      decwih_sw, decwhh_sw, WeT, emb16,
                                      wihf16, wihb16, decemb16, out, syncb);
    k_vocab<<<16, 256, 0, stream>>>(emb16, wihf16, wihb16, bf_, bb_, xg_vocab);
    k_enc<<<16, 512, 0, stream>>>(src, xg_vocab, whhf_sw, whhb_sw, enc_out, hdec0, c_ws);
    k_proj<<<2048, 256, 0, stream>>>(enc_out, WeT, proj8);
    k_qinit<<<16, 256, 0, stream>>>(hdec0, WhT_sw, qpart);
    k_dec<<<256, 512, 0, stream>>>(proj8, enc_out, qpart, attn_b, attn_v, trg,
                                   decemb16, x_sw, decwih_sw, decwhh_sw, dec_b,
                                   c_ws, hdec0, hdec1, hhist_sw, WhT_sw,
                                   part_m, part_l, part_ctx, syncb);
    k_logits<<<127, 256, 0, stream>>>(hhist_sw, outWT_sw, out_b, out);
}